// Round 1
// baseline (784.256 us; speedup 1.0000x reference)
//
#include <hip/hip_runtime.h>
#include <stdint.h>

// Problem constants
// B=2, L=2048, D=512, H=8, DK=DV=64, TEMP=8, LN_EPS=1e-5

typedef float fx4 __attribute__((ext_vector_type(4)));
typedef short bfx8 __attribute__((ext_vector_type(8)));
typedef short sx4 __attribute__((ext_vector_type(4)));

#define MFMA16(a, b, c) __builtin_amdgcn_mfma_f32_16x16x32_bf16((a), (b), (c), 0, 0, 0)

__device__ __forceinline__ unsigned short f2bf(float f) {
  union { float f; uint32_t u; } v; v.f = f;
  uint32_t r = v.u + 0x7FFFu + ((v.u >> 16) & 1u);  // RNE
  return (unsigned short)(r >> 16);
}

__device__ __forceinline__ bfx8 ldbf8(const unsigned short* p) {
  return *reinterpret_cast<const bfx8*>(p);
}

__device__ __forceinline__ bfx8 cvt8(const float* p) {
  fx4 a = *reinterpret_cast<const fx4*>(p);
  fx4 b = *reinterpret_cast<const fx4*>(p + 4);
  bfx8 r;
  r[0] = (short)f2bf(a[0]); r[1] = (short)f2bf(a[1]);
  r[2] = (short)f2bf(a[2]); r[3] = (short)f2bf(a[3]);
  r[4] = (short)f2bf(b[0]); r[5] = (short)f2bf(b[1]);
  r[6] = (short)f2bf(b[2]); r[7] = (short)f2bf(b[3]);
  return r;
}

// ---------------- kernel 0a: convert 4 weight matrices (512x512 f32) to bf16 ----
__global__ __launch_bounds__(256) void k_w2bf(const float* __restrict__ s0,
                                              const float* __restrict__ s1,
                                              const float* __restrict__ s2,
                                              const float* __restrict__ s3,
                                              unsigned short* __restrict__ dst) {
  int y = blockIdx.y;
  const float* s = (y == 0) ? s0 : (y == 1) ? s1 : (y == 2) ? s2 : s3;
  int i = (blockIdx.x * 256 + threadIdx.x) * 4;  // 256 blocks * 256 thr * 4 = 262144
  fx4 v = *reinterpret_cast<const fx4*>(s + i);
  sx4 o;
  o[0] = (short)f2bf(v[0]); o[1] = (short)f2bf(v[1]);
  o[2] = (short)f2bf(v[2]); o[3] = (short)f2bf(v[3]);
  *reinterpret_cast<sx4*>(dst + y * 262144 + i) = o;
}

// ---------------- kernel 0b: pack int mask -> bitmask (bit i of word w = mask[w*64+i]) ----
__global__ __launch_bounds__(256) void k_maskpack(const int* __restrict__ mask,
                                                  unsigned long long* __restrict__ mbits) {
  int i = blockIdx.x * 256 + threadIdx.x;  // total 8388608
  unsigned long long b = __ballot(mask[i] != 0);
  if ((threadIdx.x & 63) == 0) mbits[i >> 6] = b;
}

// ---------------- kernel 1: projection GEMM  C(4096x512) = X(4096x512) @ W^T + bias ----
// zmode 0: dst = Qb [B,H,L,64] bf16 ; 1: Kb same ; 2: Vt [B,H,64,L] bf16 (transposed)
__global__ __launch_bounds__(256) void k_proj(const float* __restrict__ X,
                                              const unsigned short* __restrict__ Wb,
                                              const float* __restrict__ bias,
                                              unsigned short* __restrict__ dst,
                                              int zmode) {
  int wave = threadIdx.x >> 6, lane = threadIdx.x & 63;
  int quad = lane >> 4, tn = lane & 15;
  int m0 = blockIdx.x * 64 + wave * 16;   // 64 blocks.x -> 4096 rows
  int n0 = blockIdx.y * 64;               // 8 blocks.y  -> 512 cols
  fx4 acc[4];
  #pragma unroll
  for (int i = 0; i < 4; ++i) acc[i] = (fx4){0.f, 0.f, 0.f, 0.f};

  const float* xrow = X + (size_t)(m0 + tn) * 512;
  for (int k0 = 0; k0 < 512; k0 += 32) {
    bfx8 af = cvt8(xrow + k0 + quad * 8);
    #pragma unroll
    for (int nt = 0; nt < 4; ++nt) {
      const unsigned short* wp = Wb + (size_t)(n0 + nt * 16 + tn) * 512 + k0 + quad * 8;
      acc[nt] = MFMA16(af, ldbf8(wp), acc[nt]);
    }
  }

  #pragma unroll
  for (int nt = 0; nt < 4; ++nt) {
    int n = n0 + nt * 16 + tn;
    int h = n >> 6, dd = n & 63;
    float bv = bias[n];
    if (zmode == 2) {
      int r0 = m0 + quad * 4;          // 4 consecutive rows, same batch
      int b = r0 >> 11, l = r0 & 2047;
      sx4 o;
      #pragma unroll
      for (int i = 0; i < 4; ++i) o[i] = (short)f2bf(acc[nt][i] + bv);
      unsigned short* vp = dst + (size_t)((b * 8 + h) * 64 + dd) * 2048 + l;
      *reinterpret_cast<sx4*>(vp) = o;
    } else {
      #pragma unroll
      for (int i = 0; i < 4; ++i) {
        int r = m0 + quad * 4 + i;
        int b = r >> 11, l = r & 2047;
        dst[(size_t)((b * 8 + h) * 2048 + l) * 64 + dd] = f2bf(acc[nt][i] + bv);
      }
    }
  }
}

// ---------------- kernel 2: attention per (b,h, 16 q-rows), 8 waves ------------
// Phase A: QK^T with gate fused (gate stream overlaps MFMA), 8 waves split keys
// Phase B: mask -> max -> exp -> sum (pure LDS+VALU), 2 rows/wave
// Phase C (waves 4..7): write normalized attn   || Phase D (waves 0..3): P~ @ V
// XCD swizzle: each XCD owns 2 bh -> K/V (1 MB) stay L2-resident.
#define SPITCH 2052
__global__ __launch_bounds__(512) void k_attn(const unsigned short* __restrict__ Qb,
                                              const unsigned short* __restrict__ Kb,
                                              const unsigned short* __restrict__ Vt,
                                              const float* __restrict__ gate,
                                              const unsigned long long* __restrict__ mbits,
                                              float* __restrict__ attn_out,
                                              unsigned short* __restrict__ Ob) {
  __shared__ float S[16 * SPITCH];   // ~128 KB gated score strip
  __shared__ float rowinv[16];

  int wave = threadIdx.x >> 6, lane = threadIdx.x & 63;
  int quad = lane >> 4, tn = lane & 15;

  // XCD-aware work assignment: lin%8 = XCD (round-robin dispatch)
  int lin = blockIdx.x;            // 0..2047
  int xcd = lin & 7;
  int ix  = lin >> 3;              // 0..255
  int bh  = xcd * 2 + (ix >> 7);   // each XCD handles exactly 2 (b,h) pairs
  int qt  = ix & 127;
  int b = bh >> 3;
  int q0 = qt * 16;

  // ---- phase A: S = (Q K^T)/8 * gate into LDS, 8 waves stride keys -----------
  const unsigned short* Qbase = Qb + ((size_t)bh * 2048 + q0) * 64;
  bfx8 aq0 = ldbf8(Qbase + tn * 64 + quad * 8);
  bfx8 aq1 = ldbf8(Qbase + tn * 64 + 32 + quad * 8);
  const unsigned short* Kbase = Kb + (size_t)bh * 2048 * 64;
  const float* gbase = gate + ((size_t)bh * 2048 + q0 + quad * 4) * 2048 + tn;
  #pragma unroll 4
  for (int kt = wave; kt < 128; kt += 8) {
    int key0 = kt * 16;
    const float* gp = gbase + key0;
    float g0 = gp[0];
    float g1 = gp[2048];
    float g2 = gp[4096];
    float g3 = gp[6144];
    const unsigned short* kp = Kbase + (size_t)(key0 + tn) * 64 + quad * 8;
    bfx8 b0 = ldbf8(kp);
    bfx8 b1 = ldbf8(kp + 32);
    fx4 d = (fx4){0.f, 0.f, 0.f, 0.f};
    d = MFMA16(aq0, b0, d);
    d = MFMA16(aq1, b1, d);
    S[(quad * 4 + 0) * SPITCH + key0 + tn] = d[0] * 0.125f * g0;
    S[(quad * 4 + 1) * SPITCH + key0 + tn] = d[1] * 0.125f * g1;
    S[(quad * 4 + 2) * SPITCH + key0 + tn] = d[2] * 0.125f * g2;
    S[(quad * 4 + 3) * SPITCH + key0 + tn] = d[3] * 0.125f * g3;
  }
  __syncthreads();

  // ---- phase B: mask -> softmax stats, wave w owns rows 2w, 2w+1 -------------
  #pragma unroll
  for (int rr = 0; rr < 2; ++rr) {
    int r = wave * 2 + rr;
    float* srow = S + r * SPITCH;
    const unsigned long long* mrow = mbits + (size_t)(b * 2048 + q0 + r) * 32;
    fx4 sv[8];
    float lmax = -3.0e38f;
    #pragma unroll
    for (int it = 0; it < 8; ++it) {
      int k4 = lane + it * 64;     // float4 index, 0..511
      fx4 s = *reinterpret_cast<fx4*>(srow + k4 * 4);
      unsigned long long mw = mrow[k4 >> 4];
      int sh = (k4 & 15) * 4;
      #pragma unroll
      for (int i = 0; i < 4; ++i) {
        float vv = s[i];
        if ((mw >> (sh + i)) & 1ull) vv = -3.0e38f;
        s[i] = vv;
        lmax = fmaxf(lmax, vv);
      }
      sv[it] = s;
    }
    #pragma unroll
    for (int off = 32; off; off >>= 1) lmax = fmaxf(lmax, __shfl_xor(lmax, off));
    float lsum = 0.f;
    #pragma unroll
    for (int it = 0; it < 8; ++it) {
      fx4 s = sv[it];
      #pragma unroll
      for (int i = 0; i < 4; ++i) {
        float p = __expf(s[i] - lmax);
        s[i] = p;
        lsum += p;
      }
      *reinterpret_cast<fx4*>(srow + (lane + it * 64) * 4) = s;  // store P~
    }
    #pragma unroll
    for (int off = 32; off; off >>= 1) lsum += __shfl_xor(lsum, off);
    if (lane == 0) rowinv[r] = 1.0f / lsum;
  }
  __syncthreads();

  int h = bh & 7;
  if (wave >= 4) {
    // ---- phase C: waves 4..7 stream normalized attention to global ----------
    int w = wave - 4;
    float* attn_base = attn_out + ((size_t)bh * 2048 + q0) * 2048;
    #pragma unroll
    for (int ri = 0; ri < 4; ++ri) {
      int r = w * 4 + ri;
      float* srow = S + r * SPITCH;
      float* orow = attn_base + (size_t)r * 2048;
      float inv = rowinv[r];
      #pragma unroll
      for (int it = 0; it < 8; ++it) {
        int k4 = lane + it * 64;
        fx4 s = *reinterpret_cast<fx4*>(srow + k4 * 4);
        s = s * inv;
        *reinterpret_cast<fx4*>(orow + k4 * 4) = s;
      }
    }
  } else {
    // ---- phase D: waves 0..3: O = P~ @ V, wave w covers dv in [16w,16w+16) ---
    fx4 acc = (fx4){0.f, 0.f, 0.f, 0.f};
    const unsigned short* vbase = Vt + ((size_t)bh * 64 + wave * 16 + tn) * 2048;
    for (int kt = 0; kt < 64; ++kt) {
      const float* pp = S + tn * SPITCH + kt * 32 + quad * 8;
      bfx8 af = cvt8(pp);                       // P~ (unnormalized) -> bf16
      bfx8 bv = ldbf8(vbase + kt * 32 + quad * 8);
      acc = MFMA16(af, bv, acc);
    }
    #pragma unroll
    for (int i = 0; i < 4; ++i) {
      int r = quad * 4 + i;
      float o = acc[i] * rowinv[r];
      int qg = q0 + r;
      Ob[(size_t)(b * 2048 + qg) * 512 + h * 64 + wave * 16 + tn] = f2bf(o);
    }
  }
}

// ---------------- kernel 3: FC + bias + residual + LayerNorm --------------------
#define XPITCH 516
__global__ __launch_bounds__(256) void k_fc_ln(const unsigned short* __restrict__ Ob,
                                               const unsigned short* __restrict__ Wfcb,
                                               const float* __restrict__ bfc,
                                               const float* __restrict__ resid,
                                               const float* __restrict__ lng,
                                               const float* __restrict__ lnb,
                                               float* __restrict__ out) {
  __shared__ float xb[16 * XPITCH];
  int wave = threadIdx.x >> 6, lane = threadIdx.x & 63;
  int quad = lane >> 4, tn = lane & 15;
  int m0 = blockIdx.x * 16;   // 256 blocks -> 4096 rows

  fx4 acc[8];
  #pragma unroll
  for (int i = 0; i < 8; ++i) acc[i] = (fx4){0.f, 0.f, 0.f, 0.f};

  const unsigned short* arow = Ob + (size_t)(m0 + tn) * 512;
  for (int k0 = 0; k0 < 512; k0 += 32) {
    bfx8 af = ldbf8(arow + k0 + quad * 8);
    #pragma unroll
    for (int nt = 0; nt < 8; ++nt) {
      const unsigned short* wp = Wfcb + (size_t)(wave * 128 + nt * 16 + tn) * 512 + k0 + quad * 8;
      acc[nt] = MFMA16(af, ldbf8(wp), acc[nt]);
    }
  }
  #pragma unroll
  for (int nt = 0; nt < 8; ++nt) {
    int col = wave * 128 + nt * 16 + tn;
    #pragma unroll
    for (int i = 0; i < 4; ++i) xb[(quad * 4 + i) * XPITCH + col] = acc[nt][i];
  }
  __syncthreads();

  #pragma unroll
  for (int ri = 0; ri < 4; ++ri) {
    int r = wave * 4 + ri;
    int row = m0 + r;
    float* xr = xb + r * XPITCH;
    const float* qr = resid + (size_t)row * 512;
    float sum = 0.f, sq = 0.f;
    #pragma unroll
    for (int it = 0; it < 2; ++it) {
      int i4 = lane + it * 64;  // 0..127
      fx4 x = *reinterpret_cast<fx4*>(xr + i4 * 4);
      fx4 bb = *reinterpret_cast<const fx4*>(bfc + i4 * 4);
      fx4 rr = *reinterpret_cast<const fx4*>(qr + i4 * 4);
      x = x + bb + rr;
      *reinterpret_cast<fx4*>(xr + i4 * 4) = x;
      sum += x[0] + x[1] + x[2] + x[3];
      sq  += x[0]*x[0] + x[1]*x[1] + x[2]*x[2] + x[3]*x[3];
    }
    #pragma unroll
    for (int off = 32; off; off >>= 1) {
      sum += __shfl_xor(sum, off);
      sq  += __shfl_xor(sq, off);
    }
    float mu = sum * (1.f / 512.f);
    float var = sq * (1.f / 512.f) - mu * mu;
    float rstd = rsqrtf(var + 1e-5f);
    #pragma unroll
    for (int it = 0; it < 2; ++it) {
      int i4 = lane + it * 64;
      fx4 x = *reinterpret_cast<fx4*>(xr + i4 * 4);
      fx4 gg = *reinterpret_cast<const fx4*>(lng + i4 * 4);
      fx4 be = *reinterpret_cast<const fx4*>(lnb + i4 * 4);
      fx4 y = (x - mu) * rstd * gg + be;
      *reinterpret_cast<fx4*>(out + (size_t)row * 512 + i4 * 4) = y;
    }
  }
}

// ---------------- launcher ------------------------------------------------------
extern "C" void kernel_launch(void* const* d_in, const int* in_sizes, int n_in,
                              void* d_out, int out_size, void* d_ws, size_t ws_size,
                              hipStream_t stream) {
  const float* q    = (const float*)d_in[0];
  const float* k    = (const float*)d_in[1];
  const float* v    = (const float*)d_in[2];
  const int*   mask = (const int*)d_in[3];
  const float* gate = (const float*)d_in[4];
  const float* w_qs = (const float*)d_in[5];
  const float* b_qs = (const float*)d_in[6];
  const float* w_ks = (const float*)d_in[7];
  const float* b_ks = (const float*)d_in[8];
  const float* w_vs = (const float*)d_in[9];
  const float* b_vs = (const float*)d_in[10];
  const float* w_fc = (const float*)d_in[11];
  const float* b_fc = (const float*)d_in[12];
  const float* ln_g = (const float*)d_in[13];
  const float* ln_b = (const float*)d_in[14];
  float* out = (float*)d_out;

  char* ws = (char*)d_ws;
  unsigned short* Qb = (unsigned short*)(ws);                    //  4 MB
  unsigned short* Kb = (unsigned short*)(ws + 4194304);          //  4 MB
  unsigned short* Vt = (unsigned short*)(ws + 8388608);          //  4 MB
  unsigned short* Ob = (unsigned short*)(ws + 12582912);         //  4 MB
  unsigned short* Wb = (unsigned short*)(ws + 16777216);         //  2 MB (4 x 512KB)
  unsigned long long* mbits = (unsigned long long*)(ws + 18874368);  // 1 MB

  k_w2bf<<<dim3(256, 4), 256, 0, stream>>>(w_qs, w_ks, w_vs, w_fc, Wb);
  k_maskpack<<<32768, 256, 0, stream>>>(mask, mbits);
  k_proj<<<dim3(64, 8), 256, 0, stream>>>(q, Wb,          b_qs, Qb, 0);
  k_proj<<<dim3(64, 8), 256, 0, stream>>>(k, Wb + 262144, b_ks, Kb, 1);
  k_proj<<<dim3(64, 8), 256, 0, stream>>>(v, Wb + 524288, b_vs, Vt, 2);
  k_attn<<<dim3(2048), 512, 0, stream>>>(Qb, Kb, Vt, gate, mbits,
                                         out + 2097152, Ob);
  k_fc_ln<<<256, 256, 0, stream>>>(Ob, Wb + 786432, b_fc, q, ln_g, ln_b, out);
}